// Round 1
// baseline (656.327 us; speedup 1.0000x reference)
//
#include <hip/hip_runtime.h>

#define GRID 64
#define NVOX (GRID*GRID*GRID)
#define NCLS 20
#define NSEED 512

// ---------------- weight transpose: [oc][ci][dz][dy][dx] -> [(nb*ci)][oc] ----------------
__global__ void transpose_w1(const float* __restrict__ w, float* __restrict__ wt) {
    int t = blockIdx.x * 256 + threadIdx.x;      // over 27*6*64
    if (t >= 27 * 6 * 64) return;
    int oc = t & 63;
    int r  = t >> 6;            // r = nb*6 + ci
    int nb = r / 6, ci = r % 6;
    wt[t] = w[oc * 162 + ci * 27 + nb];
}

__global__ void transpose_w2(const float* __restrict__ w, float* __restrict__ wt) {
    int t = blockIdx.x * 256 + threadIdx.x;      // over 27*64*32
    if (t >= 27 * 64 * 32) return;
    int oc = t & 31;
    int r  = t >> 5;            // r = nb*64 + ci
    int nb = r >> 6, ci = r & 63;
    wt[t] = w[oc * 1728 + ci * 27 + nb];
}

// ---------------- conv1 (6->64) + relu, output channel-last h1[vox][64] ----------------
__global__ __launch_bounds__(256) void conv1_kernel(
    const float* __restrict__ feat,   // [6][64][64][64]
    const float* __restrict__ w1t,    // [(nb*6+ci)][64]
    const float* __restrict__ b1,
    float* __restrict__ h1)           // [vox][64]
{
    int bx = blockIdx.x;              // z*16 + ytile
    int z  = bx >> 4, yt = bx & 15;
    int x  = threadIdx.x & 63;
    int y  = yt * 4 + (threadIdx.x >> 6);

    float acc[64];
    #pragma unroll
    for (int o = 0; o < 64; ++o) acc[o] = b1[o];

    for (int dz = -1; dz <= 1; ++dz) {
      int nz = z + dz; bool okz = (unsigned)nz < 64u; int cz = okz ? nz : (nz < 0 ? 0 : 63);
      for (int dy = -1; dy <= 1; ++dy) {
        int ny = y + dy; bool oky = (unsigned)ny < 64u; int cy = oky ? ny : (ny < 0 ? 0 : 63);
        for (int dx = -1; dx <= 1; ++dx) {
          int nx = x + dx; bool okx = (unsigned)nx < 64u; int cx = okx ? nx : (nx < 0 ? 0 : 63);
          float m = (okz && oky && okx) ? 1.0f : 0.0f;
          int nb = (dz + 1) * 9 + (dy + 1) * 3 + (dx + 1);
          int voff = (cz * 64 + cy) * 64 + cx;
          const float* wr = w1t + nb * 6 * 64;   // wave-uniform -> s_load
          #pragma unroll
          for (int ci = 0; ci < 6; ++ci) {
            float v = feat[(size_t)ci * NVOX + voff] * m;
            const float* wc = wr + ci * 64;
            #pragma unroll
            for (int o = 0; o < 64; ++o) acc[o] = fmaf(v, wc[o], acc[o]);
          }
        }
      }
    }

    float* dst = h1 + ((size_t)((z * 64 + y) * 64 + x)) * 64;
    #pragma unroll
    for (int o = 0; o < 64; o += 4) {
        float4 v = make_float4(fmaxf(acc[o], 0.f), fmaxf(acc[o+1], 0.f),
                               fmaxf(acc[o+2], 0.f), fmaxf(acc[o+3], 0.f));
        *reinterpret_cast<float4*>(dst + o) = v;
    }
}

// ------- conv2 (64->32) + relu + heads + distance argmin + mismatch scatter -------
__global__ __launch_bounds__(256) void conv2_fused_kernel(
    const float* __restrict__ h1,     // [vox][64]
    const float* __restrict__ w2t,    // [(nb*64+ci)][32]
    const float* __restrict__ b2,
    const float* __restrict__ points, // [N][3]
    const float* __restrict__ ann,    // [512][4]
    const float* __restrict__ sem_w, const float* __restrict__ sem_b,
    const float* __restrict__ off_w, const float* __restrict__ off_b,
    float* __restrict__ out_logits,   // [N][20]
    float* __restrict__ out_off,      // [N][3]
    int* __restrict__ iv_out,         // [N]  valid ? inst : -1
    int* __restrict__ bad_seed)       // [512]
{
    __shared__ float4 sseed[NSEED];
    for (int i = threadIdx.x; i < NSEED; i += 256) {
        float a0 = ann[i*4+0], a1 = ann[i*4+1], a2 = ann[i*4+2];
        sseed[i] = make_float4(a0, a1, a2, a0*a0 + a1*a1 + a2*a2);
    }
    __syncthreads();

    int bx = blockIdx.x;
    int z  = bx >> 4, yt = bx & 15;
    int x  = threadIdx.x & 63;
    int y  = yt * 4 + (threadIdx.x >> 6);
    int vox = (z * 64 + y) * 64 + x;

    float acc[32];
    #pragma unroll
    for (int o = 0; o < 32; ++o) acc[o] = b2[o];

    for (int dz = -1; dz <= 1; ++dz) {
      int nz = z + dz; bool okz = (unsigned)nz < 64u; int cz = okz ? nz : (nz < 0 ? 0 : 63);
      for (int dy = -1; dy <= 1; ++dy) {
        int ny = y + dy; bool oky = (unsigned)ny < 64u; int cy = oky ? ny : (ny < 0 ? 0 : 63);
        for (int dx = -1; dx <= 1; ++dx) {
          int nx = x + dx; bool okx = (unsigned)nx < 64u; int cx = okx ? nx : (nx < 0 ? 0 : 63);
          float m = (okz && oky && okx) ? 1.0f : 0.0f;
          int nb = (dz + 1) * 9 + (dy + 1) * 3 + (dx + 1);
          const float* src = h1 + ((size_t)((cz * 64 + cy) * 64 + cx)) * 64;
          const float* wr  = w2t + nb * 64 * 32;  // wave-uniform -> s_load
          #pragma unroll 4
          for (int c4 = 0; c4 < 16; ++c4) {
            float4 iv = *reinterpret_cast<const float4*>(src + c4 * 4);
            iv.x *= m; iv.y *= m; iv.z *= m; iv.w *= m;
            const float* wc = wr + c4 * 4 * 32;
            #pragma unroll
            for (int o = 0; o < 32; ++o) acc[o] = fmaf(iv.x, wc[o],      acc[o]);
            #pragma unroll
            for (int o = 0; o < 32; ++o) acc[o] = fmaf(iv.y, wc[32 + o], acc[o]);
            #pragma unroll
            for (int o = 0; o < 32; ++o) acc[o] = fmaf(iv.z, wc[64 + o], acc[o]);
            #pragma unroll
            for (int o = 0; o < 32; ++o) acc[o] = fmaf(iv.w, wc[96 + o], acc[o]);
          }
        }
      }
    }

    // relu -> pf
    #pragma unroll
    for (int o = 0; o < 32; ++o) acc[o] = fmaxf(acc[o], 0.f);

    // semantic head + argmax (strict > matches numpy first-occurrence)
    float best = -1e30f; int am = 0;
    #pragma unroll
    for (int c = 0; c < NCLS; ++c) {
        float l = sem_b[c];
        #pragma unroll
        for (int f = 0; f < 32; ++f) l = fmaf(acc[f], sem_w[c * 32 + f], l);
        out_logits[(size_t)vox * NCLS + c] = l;
        if (l > best) { best = l; am = c; }
    }

    // offset head
    float off[3];
    #pragma unroll
    for (int k = 0; k < 3; ++k) {
        float l = off_b[k];
        #pragma unroll
        for (int f = 0; f < 32; ++f) l = fmaf(acc[f], off_w[k * 32 + f], l);
        out_off[(size_t)vox * 3 + k] = l;
        off[k] = l;
    }

    float px = points[(size_t)vox * 3 + 0] + off[0];
    float py = points[(size_t)vox * 3 + 1] + off[1];
    float pz = points[(size_t)vox * 3 + 2] + off[2];
    float pp = px * px + py * py + pz * pz;

    // nearest seed (argmin on d2; sqrt is monotone). strict < = first-occurrence.
    float bd2 = 1e30f; int bj = 0;
    for (int j = 0; j < NSEED; ++j) {
        float4 s = sseed[j];                    // LDS broadcast, conflict-free
        float dot = px * s.x + py * s.y + pz * s.z;
        float d2  = pp + s.w - 2.0f * dot;
        if (d2 < bd2) { bd2 = d2; bj = j; }
    }
    float mind = sqrtf(fmaxf(bd2, 0.f));
    bool valid = mind < 1.5f;

    int slab = (int)ann[bj * 4 + 3];
    if (valid && am != slab) atomicOr(&bad_seed[bj], 1);
    iv_out[vox] = valid ? bj : -1;
}

// ---------------- finalize pseudo labels ----------------
__global__ void finalize_kernel(const int* __restrict__ iv,
                                const int* __restrict__ bad,
                                float* __restrict__ pl) {
    int t = blockIdx.x * 256 + threadIdx.x;
    if (t >= NVOX) return;
    int v = iv[t];
    float r = -1.0f;
    if (v >= 0 && bad[v] == 0) r = (float)v;
    pl[t] = r;
}

extern "C" void kernel_launch(void* const* d_in, const int* in_sizes, int n_in,
                              void* d_out, int out_size, void* d_ws, size_t ws_size,
                              hipStream_t stream) {
    const float* points   = (const float*)d_in[0];
    const float* features = (const float*)d_in[1];
    const float* ann      = (const float*)d_in[2];
    const float* w1       = (const float*)d_in[3];
    const float* b1       = (const float*)d_in[4];
    const float* w2       = (const float*)d_in[5];
    const float* b2       = (const float*)d_in[6];
    const float* sem_w    = (const float*)d_in[7];
    const float* sem_b    = (const float*)d_in[8];
    const float* off_w    = (const float*)d_in[9];
    const float* off_b    = (const float*)d_in[10];

    float* out        = (float*)d_out;
    float* out_logits = out;
    float* out_off    = out + (size_t)NVOX * NCLS;   // N*20
    float* out_pl     = out + (size_t)NVOX * 23;     // N*23

    // workspace layout (bytes, 256-aligned)
    char*  ws  = (char*)d_ws;
    float* w1t = (float*)(ws);                 //   41472 B
    float* w2t = (float*)(ws + 41472);         //  221184 B
    int*   bad = (int*)  (ws + 262656);        //    2048 B
    int*   iv  = (int*)  (ws + 264704);        // 1048576 B
    float* h1  = (float*)(ws + 1313280);       // 67108864 B  (total ~65.3 MB)

    hipMemsetAsync(bad, 0, NSEED * sizeof(int), stream);
    transpose_w1<<<41, 256, 0, stream>>>(w1, w1t);
    transpose_w2<<<216, 256, 0, stream>>>(w2, w2t);
    conv1_kernel<<<1024, 256, 0, stream>>>(features, w1t, b1, h1);
    conv2_fused_kernel<<<1024, 256, 0, stream>>>(h1, w2t, b2, points, ann,
        sem_w, sem_b, off_w, off_b, out_logits, out_off, iv, bad);
    finalize_kernel<<<1024, 256, 0, stream>>>(iv, bad, out_pl);
}